// Round 2
// baseline (1350.979 us; speedup 1.0000x reference)
//
#include <hip/hip_runtime.h>
#include <stdint.h>

// GCN: out = Dinv (A+I) Dinv (X W) + b, two layers, relu between.
// N=100000, E=1600000, K=128, C1=128, C2=64. All float32 (edge_index int32).

static constexpr int KD = 128;

// ---------------- degree / dinv ----------------
__global__ __launch_bounds__(256) void deg_init(float* __restrict__ deg, int n) {
    int i = blockIdx.x * 256 + threadIdx.x;
    if (i < n) deg[i] = 1.0f;  // self-loop
}
__global__ __launch_bounds__(256) void deg_count(const int* __restrict__ dst,
                                                 float* __restrict__ deg, int e) {
    int i = blockIdx.x * 256 + threadIdx.x;
    if (i < e) atomicAdd(&deg[dst[i]], 1.0f);
}
__global__ __launch_bounds__(256) void deg_rsqrt(float* __restrict__ deg, int n) {
    int i = blockIdx.x * 256 + threadIdx.x;
    if (i < n) deg[i] = rsqrtf(deg[i]);
}

// ---------------- GEMM: out[i][c] = dinv[i] * sum_k x[i][k] * W[k][c] ----------------
// 32 rows/block, 256 threads. W staged in LDS in two k=64 tiles (fp32, <=64KB static).
template<int C>
__global__ __launch_bounds__(256) void gemm_scaled(const float* __restrict__ x,
        const float* __restrict__ W, const float* __restrict__ dinv,
        float* __restrict__ out, int n)
{
    __shared__ __align__(16) float lws[64 * C];   // W k-tile
    __shared__ float lx[32][KD + 1];              // +1 pad: kill bank conflicts
    const int t = threadIdx.x;
    const int row0 = blockIdx.x * 32;

    // stage x tile (float4 reads, padded scalar writes)
    for (int i = t; i < 32 * KD / 4; i += 256) {
        int r = i >> 5, k4 = (i & 31) * 4;
        int row = row0 + r;
        float4 v = make_float4(0.f, 0.f, 0.f, 0.f);
        if (row < n) v = *reinterpret_cast<const float4*>(&x[(size_t)row * KD + k4]);
        lx[r][k4 + 0] = v.x; lx[r][k4 + 1] = v.y;
        lx[r][k4 + 2] = v.z; lx[r][k4 + 3] = v.w;
    }

    const int r  = t >> 3;         // 32 rows
    const int cb = (t & 7) * 4;    // col base within 32-col group
    constexpr int J = C / 32;      // 4 for C=128, 2 for C=64
    float acc[4 * J];
#pragma unroll
    for (int i = 0; i < 4 * J; ++i) acc[i] = 0.0f;

    for (int kt = 0; kt < 2; ++kt) {
        __syncthreads();   // kt=0: covers lx writes; kt=1: waits for lws readers
        {
            const float4* W4 = reinterpret_cast<const float4*>(W + (size_t)kt * 64 * C);
            float4* l4 = reinterpret_cast<float4*>(lws);
            for (int i = t; i < 64 * C / 4; i += 256) l4[i] = W4[i];
        }
        __syncthreads();
#pragma unroll 8
        for (int k = 0; k < 64; ++k) {
            float xv = lx[r][kt * 64 + k];
#pragma unroll
            for (int j = 0; j < J; ++j) {
                float4 wv = *reinterpret_cast<const float4*>(&lws[k * C + cb + 32 * j]);
                acc[4*j+0] += xv * wv.x;
                acc[4*j+1] += xv * wv.y;
                acc[4*j+2] += xv * wv.z;
                acc[4*j+3] += xv * wv.w;
            }
        }
    }

    int row = row0 + r;
    if (row < n) {
        float s = dinv[row];
#pragma unroll
        for (int j = 0; j < J; ++j) {
            float4 v = make_float4(acc[4*j+0]*s, acc[4*j+1]*s, acc[4*j+2]*s, acc[4*j+3]*s);
            *reinterpret_cast<float4*>(&out[(size_t)row * C + cb + 32 * j]) = v;
        }
    }
}

// ---------------- edge scatter: acc[dst] += h[src] ----------------
template<int C>
__global__ __launch_bounds__(256) void scatter_add(const int* __restrict__ src,
        const int* __restrict__ dst, const float* __restrict__ h,
        float* __restrict__ acc, long long total)
{
    long long idx = (long long)blockIdx.x * 256 + threadIdx.x;
    if (idx >= total) return;
    int e = (int)(idx >> (C == 128 ? 7 : 6));
    int c = (int)(idx & (C - 1));
    int s = src[e], d = dst[e];
    atomicAdd(&acc[(size_t)d * C + c], h[(size_t)s * C + c]);
}

// ---------------- epilogues (float4) ----------------
__global__ __launch_bounds__(256) void finalize_relu(float* __restrict__ acc,
        const float* __restrict__ dinv, const float* __restrict__ b, int n)
{
    size_t i4 = (size_t)blockIdx.x * 256 + threadIdx.x;
    if (i4 >= (size_t)n * KD / 4) return;
    size_t idx = i4 * 4;
    int row = (int)(idx >> 7);
    int c = (int)(idx & (KD - 1));
    float s = dinv[row];
    float4 a = reinterpret_cast<float4*>(acc)[i4];
    a.x = fmaxf(s * a.x + b[c + 0], 0.0f);
    a.y = fmaxf(s * a.y + b[c + 1], 0.0f);
    a.z = fmaxf(s * a.z + b[c + 2], 0.0f);
    a.w = fmaxf(s * a.w + b[c + 3], 0.0f);
    reinterpret_cast<float4*>(acc)[i4] = a;
}

__global__ __launch_bounds__(256) void finalize_out(const float* __restrict__ acc,
        const float* __restrict__ dinv, const float* __restrict__ b,
        float* __restrict__ out, int n)
{
    size_t i4 = (size_t)blockIdx.x * 256 + threadIdx.x;
    if (i4 >= (size_t)n * 64 / 4) return;
    size_t idx = i4 * 4;
    int row = (int)(idx >> 6);
    int c = (int)(idx & 63);
    float s = dinv[row];
    float4 a = reinterpret_cast<const float4*>(acc)[i4];
    a.x = s * a.x + b[c + 0];
    a.y = s * a.y + b[c + 1];
    a.z = s * a.z + b[c + 2];
    a.w = s * a.w + b[c + 3];
    reinterpret_cast<float4*>(out)[i4] = a;
}

extern "C" void kernel_launch(void* const* d_in, const int* in_sizes, int n_in,
                              void* d_out, int out_size, void* d_ws, size_t ws_size,
                              hipStream_t stream)
{
    const int* ei = (const int*)d_in[0];
    const int E = in_sizes[0] / 2;
    const float* emb = (const float*)d_in[1];
    const int N = in_sizes[1] / KD;
    const float* W1 = (const float*)d_in[2];
    const float* b1 = (const float*)d_in[3];
    const float* W2 = (const float*)d_in[4];
    const float* b2 = (const float*)d_in[5];
    const int* src = ei;        // edge_index[0]
    const int* dst = ei + E;    // edge_index[1]

    // workspace layout (fp32):
    //   dinv : N
    //   h1   : N*128   (layer-1 pre-agg; reused as h2 [N*64] + acc2 [N*64])
    //   acc1 : N*128   (layer-1 aggregate -> x after relu)
    float* dinv = (float*)d_ws;
    float* h1   = dinv + N;
    float* acc1 = h1 + (size_t)N * KD;
    float* h2   = h1;
    float* acc2 = h1 + (size_t)N * 64;

    // degrees -> dinv
    deg_init <<<(N + 255) / 256, 256, 0, stream>>>(dinv, N);
    deg_count<<<(E + 255) / 256, 256, 0, stream>>>(dst, dinv, E);
    deg_rsqrt<<<(N + 255) / 256, 256, 0, stream>>>(dinv, N);

    // ---- layer 1: h1 = dinv * (emb @ W1); acc1 = h1 (self) + scatter; relu ----
    gemm_scaled<128><<<(N + 31) / 32, 256, 0, stream>>>(emb, W1, dinv, h1, N);
    hipMemcpyAsync(acc1, h1, (size_t)N * KD * sizeof(float), hipMemcpyDeviceToDevice, stream);
    {
        long long tot = (long long)E * 128;
        scatter_add<128><<<(int)((tot + 255) / 256), 256, 0, stream>>>(src, dst, h1, acc1, tot);
    }
    finalize_relu<<<(int)(((size_t)N * KD / 4 + 255) / 256), 256, 0, stream>>>(acc1, dinv, b1, N);

    // ---- layer 2: h2 = dinv * (x @ W2); acc2 = h2 + scatter; out = acc2*dinv + b2 ----
    gemm_scaled<64><<<(N + 31) / 32, 256, 0, stream>>>(acc1, W2, dinv, h2, N);
    hipMemcpyAsync(acc2, h2, (size_t)N * 64 * sizeof(float), hipMemcpyDeviceToDevice, stream);
    {
        long long tot = (long long)E * 64;
        scatter_add<64><<<(int)((tot + 255) / 256), 256, 0, stream>>>(src, dst, h2, acc2, tot);
    }
    finalize_out<<<(int)(((size_t)N * 64 / 4 + 255) / 256), 256, 0, stream>>>(acc2, dinv, b2,
        (float*)d_out, N);
}

// Round 3
// 721.993 us; speedup vs baseline: 1.8712x; 1.8712x over previous
//
#include <hip/hip_runtime.h>
#include <stdint.h>

// GCN: out = Dinv (A+I) Dinv (X W) + b, two layers, relu between.
// N=100000, E=1600000, K=128, C1=128, C2=64. All float32 (edge_index int32).
// R2: CSR gather-reduce replaces atomic scatter (800MB atomic write-through -> 51MB streaming write).

static constexpr int KD = 128;

// ---------------- degree histogram (int) ----------------
__global__ __launch_bounds__(256) void deg_count(const int* __restrict__ dst,
                                                 int* __restrict__ deg, int e) {
    int i = blockIdx.x * 256 + threadIdx.x;
    if (i < e) atomicAdd(&deg[dst[i]], 1);
}

// ---------------- exclusive scan (3 passes), 1024 elems/block ----------------
__global__ __launch_bounds__(256) void scan1(const int* __restrict__ deg,
        int* __restrict__ roff, int* __restrict__ bsum, int n) {
    __shared__ int wsum[4];
    const int t = threadIdx.x;
    const int base = blockIdx.x * 1024 + t * 4;
    int d0 = 0, d1 = 0, d2 = 0, d3 = 0;
    if (base + 0 < n) d0 = deg[base + 0];
    if (base + 1 < n) d1 = deg[base + 1];
    if (base + 2 < n) d2 = deg[base + 2];
    if (base + 3 < n) d3 = deg[base + 3];
    int tsum = d0 + d1 + d2 + d3;
    // wave inclusive scan of tsum
    int lane = t & 63, wv = t >> 6;
    int v = tsum;
    for (int off = 1; off < 64; off <<= 1) {
        int u = __shfl_up(v, off, 64);
        if (lane >= off) v += u;
    }
    if (lane == 63) wsum[wv] = v;
    __syncthreads();
    int woff = 0;
    for (int i = 0; i < wv; ++i) woff += wsum[i];
    int excl = v - tsum + woff;   // exclusive prefix within block
    if (base + 0 < n) roff[base + 0] = excl;
    if (base + 1 < n) roff[base + 1] = excl + d0;
    if (base + 2 < n) roff[base + 2] = excl + d0 + d1;
    if (base + 3 < n) roff[base + 3] = excl + d0 + d1 + d2;
    if (t == 255) bsum[blockIdx.x] = excl + tsum;  // block total
}

__global__ __launch_bounds__(256) void scan2(int* __restrict__ bsum, int nb) {
    if (threadIdx.x == 0) {
        int run = 0;
        for (int i = 0; i < nb; ++i) { int v = bsum[i]; bsum[i] = run; run += v; }
    }
}

// roff[i] += bsum[blk]; cursor (=deg array, reused) <- roff; dinv = rsqrt(1+deg)
__global__ __launch_bounds__(256) void scan3(int* __restrict__ roff,
        const int* __restrict__ bsum, int* __restrict__ cursor_deg,
        float* __restrict__ dinv, int n, int e_total) {
    int i = blockIdx.x * 256 + threadIdx.x;
    if (i >= n) return;
    int d = cursor_deg[i];
    dinv[i] = rsqrtf((float)(d + 1));
    int v = roff[i] + bsum[i >> 10];
    roff[i] = v;
    cursor_deg[i] = v;          // becomes fill cursor
    if (i == 0) roff[n] = e_total;
}

// ---------------- CSR fill ----------------
__global__ __launch_bounds__(256) void csr_fill(const int* __restrict__ src,
        const int* __restrict__ dst, int* __restrict__ cursor,
        int* __restrict__ csr, int e) {
    int i = blockIdx.x * 256 + threadIdx.x;
    if (i >= e) return;
    int d = dst[i];
    int slot = atomicAdd(&cursor[d], 1);
    csr[slot] = src[i];
}

// ---------------- GEMM: out[i][c] = dinv[i] * sum_k x[i][k] * W[k][c] ----------------
template<int C>
__global__ __launch_bounds__(256) void gemm_scaled(const float* __restrict__ x,
        const float* __restrict__ W, const float* __restrict__ dinv,
        float* __restrict__ out, int n)
{
    __shared__ __align__(16) float lws[64 * C];   // W k-tile
    __shared__ float lx[32][KD + 1];
    const int t = threadIdx.x;
    const int row0 = blockIdx.x * 32;

    for (int i = t; i < 32 * KD / 4; i += 256) {
        int r = i >> 5, k4 = (i & 31) * 4;
        int row = row0 + r;
        float4 v = make_float4(0.f, 0.f, 0.f, 0.f);
        if (row < n) v = *reinterpret_cast<const float4*>(&x[(size_t)row * KD + k4]);
        lx[r][k4 + 0] = v.x; lx[r][k4 + 1] = v.y;
        lx[r][k4 + 2] = v.z; lx[r][k4 + 3] = v.w;
    }

    const int r  = t >> 3;
    const int cb = (t & 7) * 4;
    constexpr int J = C / 32;
    float acc[4 * J];
#pragma unroll
    for (int i = 0; i < 4 * J; ++i) acc[i] = 0.0f;

    for (int kt = 0; kt < 2; ++kt) {
        __syncthreads();
        {
            const float4* W4 = reinterpret_cast<const float4*>(W + (size_t)kt * 64 * C);
            float4* l4 = reinterpret_cast<float4*>(lws);
            for (int i = t; i < 64 * C / 4; i += 256) l4[i] = W4[i];
        }
        __syncthreads();
#pragma unroll 8
        for (int k = 0; k < 64; ++k) {
            float xv = lx[r][kt * 64 + k];
#pragma unroll
            for (int j = 0; j < J; ++j) {
                float4 wv = *reinterpret_cast<const float4*>(&lws[k * C + cb + 32 * j]);
                acc[4*j+0] += xv * wv.x;
                acc[4*j+1] += xv * wv.y;
                acc[4*j+2] += xv * wv.z;
                acc[4*j+3] += xv * wv.w;
            }
        }
    }

    int row = row0 + r;
    if (row < n) {
        float s = dinv[row];
#pragma unroll
        for (int j = 0; j < J; ++j) {
            float4 v = make_float4(acc[4*j+0]*s, acc[4*j+1]*s, acc[4*j+2]*s, acc[4*j+3]*s);
            *reinterpret_cast<float4*>(&out[(size_t)row * C + cb + 32 * j]) = v;
        }
    }
}

// ---------------- gather-aggregate: one wave per node ----------------
// acc = h[v] + sum_{u in N(v)} h[u]; out = (relu?)(dinv[v]*acc + b)
template<bool RELU>
__global__ __launch_bounds__(256) void gather128(const float* __restrict__ h,
        const int* __restrict__ roff, const int* __restrict__ csr,
        const float* __restrict__ dinv, const float* __restrict__ b,
        float* __restrict__ out, int n)
{
    int wid = (blockIdx.x * 256 + threadIdx.x) >> 6;
    int lane = threadIdx.x & 63;
    if (wid >= n) return;
    const float2* h2 = (const float2*)h;
    float2 acc = h2[(size_t)wid * 64 + lane];   // self loop
    int e0 = roff[wid], e1 = roff[wid + 1];
    int u = (e0 < e1) ? csr[e0] : 0;
    for (int e = e0; e < e1; ++e) {
        int un = (e + 1 < e1) ? csr[e + 1] : 0;  // prefetch next index
        float2 t = h2[(size_t)u * 64 + lane];
        acc.x += t.x; acc.y += t.y;
        u = un;
    }
    float s = dinv[wid];
    float2 bb = ((const float2*)b)[lane];
    acc.x = s * acc.x + bb.x;
    acc.y = s * acc.y + bb.y;
    if (RELU) { acc.x = fmaxf(acc.x, 0.f); acc.y = fmaxf(acc.y, 0.f); }
    ((float2*)out)[(size_t)wid * 64 + lane] = acc;
}

template<bool RELU>
__global__ __launch_bounds__(256) void gather64(const float* __restrict__ h,
        const int* __restrict__ roff, const int* __restrict__ csr,
        const float* __restrict__ dinv, const float* __restrict__ b,
        float* __restrict__ out, int n)
{
    int wid = (blockIdx.x * 256 + threadIdx.x) >> 6;
    int lane = threadIdx.x & 63;
    if (wid >= n) return;
    float acc = h[(size_t)wid * 64 + lane];     // self loop
    int e0 = roff[wid], e1 = roff[wid + 1];
    int u = (e0 < e1) ? csr[e0] : 0;
    for (int e = e0; e < e1; ++e) {
        int un = (e + 1 < e1) ? csr[e + 1] : 0;
        acc += h[(size_t)u * 64 + lane];
        u = un;
    }
    float v = dinv[wid] * acc + b[lane];
    if (RELU) v = fmaxf(v, 0.f);
    out[(size_t)wid * 64 + lane] = v;
}

extern "C" void kernel_launch(void* const* d_in, const int* in_sizes, int n_in,
                              void* d_out, int out_size, void* d_ws, size_t ws_size,
                              hipStream_t stream)
{
    const int* ei = (const int*)d_in[0];
    const int E = in_sizes[0] / 2;
    const float* emb = (const float*)d_in[1];
    const int N = in_sizes[1] / KD;
    const float* W1 = (const float*)d_in[2];
    const float* b1 = (const float*)d_in[3];
    const float* W2 = (const float*)d_in[4];
    const float* b2 = (const float*)d_in[5];
    const int* src = ei;        // edge_index[0]
    const int* dst = ei + E;    // edge_index[1]

    // ---- workspace layout ----
    char* p = (char*)d_ws;
    auto alloc = [&](size_t bytes) { char* q = p; p += (bytes + 255) & ~(size_t)255; return q; };
    float* h1     = (float*)alloc((size_t)N * 128 * sizeof(float)); // gemm1 out; reused as h2 [N*64]
    float* x2     = (float*)alloc((size_t)N * 128 * sizeof(float)); // layer-1 activations
    int*   csr    = (int*)  alloc((size_t)E * sizeof(int));
    int*   roff   = (int*)  alloc((size_t)(N + 1) * sizeof(int));
    int*   deg    = (int*)  alloc((size_t)N * sizeof(int));         // reused as fill cursor
    int*   bsum   = (int*)  alloc(1024 * sizeof(int));
    float* dinv   = (float*)alloc((size_t)N * sizeof(float));
    float* h2     = h1;                                             // alias (h1 dead after gather128)

    const int nb = (N + 1023) / 1024;

    // ---- CSR build ----
    hipMemsetAsync(deg, 0, (size_t)N * sizeof(int), stream);
    deg_count<<<(E + 255) / 256, 256, 0, stream>>>(dst, deg, E);
    scan1<<<nb, 256, 0, stream>>>(deg, roff, bsum, N);
    scan2<<<1, 256, 0, stream>>>(bsum, nb);
    scan3<<<(N + 255) / 256, 256, 0, stream>>>(roff, bsum, deg, dinv, N, E);
    csr_fill<<<(E + 255) / 256, 256, 0, stream>>>(src, dst, deg, csr, E);

    // ---- layer 1 ----
    gemm_scaled<128><<<(N + 31) / 32, 256, 0, stream>>>(emb, W1, dinv, h1, N);
    gather128<true><<<(N + 3) / 4, 256, 0, stream>>>(h1, roff, csr, dinv, b1, x2, N);

    // ---- layer 2 ----
    gemm_scaled<64><<<(N + 31) / 32, 256, 0, stream>>>(x2, W2, dinv, h2, N);
    gather64<false><<<(N + 3) / 4, 256, 0, stream>>>(h2, roff, csr, dinv, b2, (float*)d_out, N);
}

// Round 4
// 567.308 us; speedup vs baseline: 2.3814x; 1.2727x over previous
//
#include <hip/hip_runtime.h>
#include <stdint.h>

// GCN: out = Dinv (A+I) Dinv (X W) + b, two layers, relu between.
// N=100000, E=1600000, K=128, C1=128, C2=64. All float32 (edge_index int32).
// R3: CSR gather-reduce (R2) + register-tiled GEMM (4x8 per thread) + unroll-4 gather MLP.

static constexpr int KD = 128;

// ---------------- degree histogram (int) ----------------
__global__ __launch_bounds__(256) void deg_count(const int* __restrict__ dst,
                                                 int* __restrict__ deg, int e) {
    int i = blockIdx.x * 256 + threadIdx.x;
    if (i < e) atomicAdd(&deg[dst[i]], 1);
}

// ---------------- exclusive scan (3 passes), 1024 elems/block ----------------
__global__ __launch_bounds__(256) void scan1(const int* __restrict__ deg,
        int* __restrict__ roff, int* __restrict__ bsum, int n) {
    __shared__ int wsum[4];
    const int t = threadIdx.x;
    const int base = blockIdx.x * 1024 + t * 4;
    int d0 = 0, d1 = 0, d2 = 0, d3 = 0;
    if (base + 0 < n) d0 = deg[base + 0];
    if (base + 1 < n) d1 = deg[base + 1];
    if (base + 2 < n) d2 = deg[base + 2];
    if (base + 3 < n) d3 = deg[base + 3];
    int tsum = d0 + d1 + d2 + d3;
    int lane = t & 63, wv = t >> 6;
    int v = tsum;
    for (int off = 1; off < 64; off <<= 1) {
        int u = __shfl_up(v, off, 64);
        if (lane >= off) v += u;
    }
    if (lane == 63) wsum[wv] = v;
    __syncthreads();
    int woff = 0;
    for (int i = 0; i < wv; ++i) woff += wsum[i];
    int excl = v - tsum + woff;
    if (base + 0 < n) roff[base + 0] = excl;
    if (base + 1 < n) roff[base + 1] = excl + d0;
    if (base + 2 < n) roff[base + 2] = excl + d0 + d1;
    if (base + 3 < n) roff[base + 3] = excl + d0 + d1 + d2;
    if (t == 255) bsum[blockIdx.x] = excl + tsum;
}

__global__ __launch_bounds__(256) void scan2(int* __restrict__ bsum, int nb) {
    __shared__ int buf[256];
    int t = threadIdx.x;
    if (nb <= 256) {
        int v = (t < nb) ? bsum[t] : 0;
        buf[t] = v;
        __syncthreads();
        for (int off = 1; off < 256; off <<= 1) {
            int u = (t >= off) ? buf[t - off] : 0;
            __syncthreads();
            buf[t] += u;
            __syncthreads();
        }
        if (t < nb) bsum[t] = buf[t] - v;   // exclusive
    } else if (t == 0) {
        int run = 0;
        for (int i = 0; i < nb; ++i) { int v = bsum[i]; bsum[i] = run; run += v; }
    }
}

__global__ __launch_bounds__(256) void scan3(int* __restrict__ roff,
        const int* __restrict__ bsum, int* __restrict__ cursor_deg,
        float* __restrict__ dinv, int n, int e_total) {
    int i = blockIdx.x * 256 + threadIdx.x;
    if (i >= n) return;
    int d = cursor_deg[i];
    dinv[i] = rsqrtf((float)(d + 1));
    int v = roff[i] + bsum[i >> 10];
    roff[i] = v;
    cursor_deg[i] = v;
    if (i == 0) roff[n] = e_total;
}

// ---------------- CSR fill ----------------
__global__ __launch_bounds__(256) void csr_fill(const int* __restrict__ src,
        const int* __restrict__ dst, int* __restrict__ cursor,
        int* __restrict__ csr, int e) {
    int i = blockIdx.x * 256 + threadIdx.x;
    if (i >= e) return;
    int d = dst[i];
    int slot = atomicAdd(&cursor[d], 1);
    csr[slot] = src[i];
}

// ---------------- register-tiled GEMM: out[i][c] = dinv[i] * sum_k x[i][k]*W[k][c] ----
// 64 rows x C cols per block, 256 threads, thread tile 4 rows x CT cols.
// LDS: lx 64x(128+2) fp32 (~33KB) + W k-stage (16KB) => ~49KB, 3 blocks/CU.
template<int C, int KSTAGE>
__global__ __launch_bounds__(256) void gemm_tiled(const float* __restrict__ x,
        const float* __restrict__ W, const float* __restrict__ dinv,
        float* __restrict__ out, int n)
{
    constexpr int CT = C / 16;                  // 8 for C=128, 4 for C=64
    __shared__ __align__(16) float lws[KSTAGE * C];
    __shared__ float lx[64][KD + 2];            // +2: float2-aligned, conflict-safe
    const int t = threadIdx.x;
    const int row0 = blockIdx.x * 64;

    // stage x: coalesced float4 reads, scalar padded writes
    for (int i = t; i < 64 * (KD / 4); i += 256) {
        int r = i >> 5, k4 = (i & 31) * 4;
        int row = row0 + r;
        float4 v = make_float4(0.f, 0.f, 0.f, 0.f);
        if (row < n) v = *reinterpret_cast<const float4*>(&x[(size_t)row * KD + k4]);
        lx[r][k4 + 0] = v.x; lx[r][k4 + 1] = v.y;
        lx[r][k4 + 2] = v.z; lx[r][k4 + 3] = v.w;
    }

    const int ty = t >> 4;          // 16 row-groups of 4 rows
    const int tx = t & 15;          // 16 col-groups of CT cols
    const int r0 = ty * 4;
    const int cb = tx * CT;

    float acc[4][CT];
#pragma unroll
    for (int i = 0; i < 4; ++i)
#pragma unroll
        for (int j = 0; j < CT; ++j) acc[i][j] = 0.0f;

    for (int kt = 0; kt < KD / KSTAGE; ++kt) {
        __syncthreads();
        {
            const float4* W4 = reinterpret_cast<const float4*>(W + (size_t)kt * KSTAGE * C);
            float4* l4 = reinterpret_cast<float4*>(lws);
            for (int i = t; i < KSTAGE * C / 4; i += 256) l4[i] = W4[i];
        }
        __syncthreads();
        const int kb = kt * KSTAGE;
#pragma unroll 4
        for (int k = 0; k < KSTAGE; k += 2) {
            float2 xv[4];
#pragma unroll
            for (int i = 0; i < 4; ++i)
                xv[i] = *reinterpret_cast<const float2*>(&lx[r0 + i][kb + k]);
#pragma unroll
            for (int kk = 0; kk < 2; ++kk) {
#pragma unroll
                for (int j = 0; j < CT / 4; ++j) {
                    float4 wv = *reinterpret_cast<const float4*>(&lws[(k + kk) * C + cb + 4 * j]);
#pragma unroll
                    for (int i = 0; i < 4; ++i) {
                        float xs = kk ? xv[i].y : xv[i].x;
                        acc[i][4*j+0] += xs * wv.x;
                        acc[i][4*j+1] += xs * wv.y;
                        acc[i][4*j+2] += xs * wv.z;
                        acc[i][4*j+3] += xs * wv.w;
                    }
                }
            }
        }
    }

#pragma unroll
    for (int i = 0; i < 4; ++i) {
        int row = row0 + r0 + i;
        if (row < n) {
            float s = dinv[row];
#pragma unroll
            for (int j = 0; j < CT / 4; ++j) {
                float4 v = make_float4(acc[i][4*j+0]*s, acc[i][4*j+1]*s,
                                       acc[i][4*j+2]*s, acc[i][4*j+3]*s);
                *reinterpret_cast<float4*>(&out[(size_t)row * C + cb + 4*j]) = v;
            }
        }
    }
}

// ---------------- gather-aggregate: one wave per node, unroll-4 for MLP ----------------
template<bool RELU>
__global__ __launch_bounds__(256) void gather128(const float* __restrict__ h,
        const int* __restrict__ roff, const int* __restrict__ csr,
        const float* __restrict__ dinv, const float* __restrict__ b,
        float* __restrict__ out, int n)
{
    int wid = (blockIdx.x * 256 + threadIdx.x) >> 6;
    int lane = threadIdx.x & 63;
    if (wid >= n) return;
    const float2* hl = (const float2*)h + lane;
    float2 acc = hl[(size_t)wid * 64];          // self loop
    float2 a1 = make_float2(0.f, 0.f);
    int e0 = roff[wid], e1 = roff[wid + 1];
    int e = e0;
    for (; e + 4 <= e1; e += 4) {
        int u0 = csr[e], u1 = csr[e+1], u2 = csr[e+2], u3 = csr[e+3];
        float2 t0 = hl[(size_t)u0 * 64];
        float2 t1 = hl[(size_t)u1 * 64];
        float2 t2 = hl[(size_t)u2 * 64];
        float2 t3 = hl[(size_t)u3 * 64];
        acc.x += t0.x + t1.x; acc.y += t0.y + t1.y;
        a1.x  += t2.x + t3.x; a1.y  += t2.y + t3.y;
    }
    for (; e < e1; ++e) {
        float2 t = hl[(size_t)csr[e] * 64];
        acc.x += t.x; acc.y += t.y;
    }
    acc.x += a1.x; acc.y += a1.y;
    float s = dinv[wid];
    float2 bb = ((const float2*)b)[lane];
    acc.x = s * acc.x + bb.x;
    acc.y = s * acc.y + bb.y;
    if (RELU) { acc.x = fmaxf(acc.x, 0.f); acc.y = fmaxf(acc.y, 0.f); }
    ((float2*)out)[(size_t)wid * 64 + lane] = acc;
}

template<bool RELU>
__global__ __launch_bounds__(256) void gather64(const float* __restrict__ h,
        const int* __restrict__ roff, const int* __restrict__ csr,
        const float* __restrict__ dinv, const float* __restrict__ b,
        float* __restrict__ out, int n)
{
    int wid = (blockIdx.x * 256 + threadIdx.x) >> 6;
    int lane = threadIdx.x & 63;
    if (wid >= n) return;
    const float* hl = h + lane;
    float acc = hl[(size_t)wid * 64];           // self loop
    float a1 = 0.f;
    int e0 = roff[wid], e1 = roff[wid + 1];
    int e = e0;
    for (; e + 4 <= e1; e += 4) {
        int u0 = csr[e], u1 = csr[e+1], u2 = csr[e+2], u3 = csr[e+3];
        float t0 = hl[(size_t)u0 * 64];
        float t1 = hl[(size_t)u1 * 64];
        float t2 = hl[(size_t)u2 * 64];
        float t3 = hl[(size_t)u3 * 64];
        acc += t0 + t1;
        a1  += t2 + t3;
    }
    for (; e < e1; ++e) acc += hl[(size_t)csr[e] * 64];
    acc += a1;
    float v = dinv[wid] * acc + b[lane];
    if (RELU) v = fmaxf(v, 0.f);
    out[(size_t)wid * 64 + lane] = v;
}

extern "C" void kernel_launch(void* const* d_in, const int* in_sizes, int n_in,
                              void* d_out, int out_size, void* d_ws, size_t ws_size,
                              hipStream_t stream)
{
    const int* ei = (const int*)d_in[0];
    const int E = in_sizes[0] / 2;
    const float* emb = (const float*)d_in[1];
    const int N = in_sizes[1] / KD;
    const float* W1 = (const float*)d_in[2];
    const float* b1 = (const float*)d_in[3];
    const float* W2 = (const float*)d_in[4];
    const float* b2 = (const float*)d_in[5];
    const int* src = ei;        // edge_index[0]
    const int* dst = ei + E;    // edge_index[1]

    // ---- workspace layout ----
    char* p = (char*)d_ws;
    auto alloc = [&](size_t bytes) { char* q = p; p += (bytes + 255) & ~(size_t)255; return q; };
    float* h1     = (float*)alloc((size_t)N * 128 * sizeof(float)); // gemm1 out; reused as h2 [N*64]
    float* x2     = (float*)alloc((size_t)N * 128 * sizeof(float)); // layer-1 activations
    int*   csr    = (int*)  alloc((size_t)E * sizeof(int));
    int*   roff   = (int*)  alloc((size_t)(N + 1) * sizeof(int));
    int*   deg    = (int*)  alloc((size_t)N * sizeof(int));         // reused as fill cursor
    int*   bsum   = (int*)  alloc(1024 * sizeof(int));
    float* dinv   = (float*)alloc((size_t)N * sizeof(float));
    float* h2     = h1;

    const int nb = (N + 1023) / 1024;

    // ---- CSR build ----
    hipMemsetAsync(deg, 0, (size_t)N * sizeof(int), stream);
    deg_count<<<(E + 255) / 256, 256, 0, stream>>>(dst, deg, E);
    scan1<<<nb, 256, 0, stream>>>(deg, roff, bsum, N);
    scan2<<<1, 256, 0, stream>>>(bsum, nb);
    scan3<<<(N + 255) / 256, 256, 0, stream>>>(roff, bsum, deg, dinv, N, E);
    csr_fill<<<(E + 255) / 256, 256, 0, stream>>>(src, dst, deg, csr, E);

    // ---- layer 1 ----
    gemm_tiled<128, 32><<<(N + 63) / 64, 256, 0, stream>>>(emb, W1, dinv, h1, N);
    gather128<true><<<(N + 3) / 4, 256, 0, stream>>>(h1, roff, csr, dinv, b1, x2, N);

    // ---- layer 2 ----
    gemm_tiled<64, 64><<<(N + 63) / 64, 256, 0, stream>>>(x2, W2, dinv, h2, N);
    gather64<false><<<(N + 3) / 4, 256, 0, stream>>>(h2, roff, csr, dinv, b2, (float*)d_out, N);
}